// Round 9
// baseline (264.626 us; speedup 1.0000x reference)
//
#include <hip/hip_runtime.h>
#include <stdint.h>

typedef float f4 __attribute__((ext_vector_type(4)));

__device__ __forceinline__ double dot4d(f4 a, f4 b) {
    return (double)a.x * (double)b.x + (double)a.y * (double)b.y
         + (double)a.z * (double)b.z + (double)a.w * (double)b.w;
}

// ---------------------------------------------------------------------------
// K1: scores, high-occupancy. 256 threads = 16 lane-groups x 4 rows = 64 rows
// per block; grid = F*T/64 = 2304 (9 blocks/CU -> up to 32 waves/CU).
// Inner loop bitwise-identical to R8 phase 1 (22 f4/lane, 4 f64 accs,
// width-16 shfl reduce).
// ---------------------------------------------------------------------------
template <int T, int D>
__global__ __launch_bounds__(256)
void score_k(const float* __restrict__ x,
             const float* __restrict__ pre_w,
             const float* __restrict__ pre_b,
             double* __restrict__ s) {
    constexpr int N4 = D / 4;            // 352
    __shared__ f4 w_sh[N4];

    const int tid  = threadIdx.x;
    const int sub  = tid & 15;
    const int gid  = tid >> 4;           // 0..15
    const int base = blockIdx.x * 64;

    for (int i = tid; i < N4; i += 256) w_sh[i] = ((const f4*)pre_w)[i];
    __syncthreads();

    const double pb = (double)pre_b[0];
    #pragma unroll
    for (int m = 0; m < 4; ++m) {
        const int r = base + gid + 16 * m;
        const f4* xr = (const f4*)(x + (size_t)r * D);
        double a0 = 0, a1 = 0, a2 = 0, a3 = 0;
        #pragma unroll 2
        for (int j = 0; j < 16; j += 4) {
            f4 v0 = xr[sub + 16 * (j + 0)];
            f4 v1 = xr[sub + 16 * (j + 1)];
            f4 v2 = xr[sub + 16 * (j + 2)];
            f4 v3 = xr[sub + 16 * (j + 3)];
            a0 += dot4d(v0, w_sh[sub + 16 * (j + 0)]);
            a1 += dot4d(v1, w_sh[sub + 16 * (j + 1)]);
            a2 += dot4d(v2, w_sh[sub + 16 * (j + 2)]);
            a3 += dot4d(v3, w_sh[sub + 16 * (j + 3)]);
        }
        {   // tail j = 16..21
            f4 v0 = xr[sub + 16 * 16];
            f4 v1 = xr[sub + 16 * 17];
            f4 v2 = xr[sub + 16 * 18];
            f4 v3 = xr[sub + 16 * 19];
            f4 v4 = xr[sub + 16 * 20];
            f4 v5 = xr[sub + 16 * 21];
            a0 += dot4d(v0, w_sh[sub + 16 * 16]);
            a1 += dot4d(v1, w_sh[sub + 16 * 17]);
            a2 += dot4d(v2, w_sh[sub + 16 * 18]);
            a3 += dot4d(v3, w_sh[sub + 16 * 19]);
            a0 += dot4d(v4, w_sh[sub + 16 * 20]);
            a1 += dot4d(v5, w_sh[sub + 16 * 21]);
        }
        double a = (a0 + a1) + (a2 + a3);
        a += __shfl_down(a, 8, 16);
        a += __shfl_down(a, 4, 16);
        a += __shfl_down(a, 2, 16);
        a += __shfl_down(a, 1, 16);
        if (sub == 0) s[r] = a + pb;
    }
}

// ---------------------------------------------------------------------------
// K2: select (R8 phases 2+3 verbatim). One block of T threads per frame.
// GEMV logits (f64, 16 accs) + rank-select (value desc, index asc) ==
// stable top-K of argsort(-softmax) (softmax monotonic -> skipped) +
// bitmask/popcount compaction -> ascending token indices.
// ---------------------------------------------------------------------------
template <int T, int K>
__global__ __launch_bounds__(T)
void select_k(const double* __restrict__ s,
              const float* __restrict__ W,
              const float* __restrict__ bias,
              int* __restrict__ idx_out) {
    constexpr int NW = (T + 31) / 32;
    __shared__ double   s_sh[T];
    __shared__ double   lg[T];
    __shared__ unsigned flags[NW];

    const int f   = blockIdx.x;
    const int tid = threadIdx.x;

    s_sh[tid] = s[(size_t)f * T + tid];
    if (tid < NW) flags[tid] = 0u;
    __syncthreads();

    {
        const float* Wc = W + tid;
        double acc[16];
        #pragma unroll
        for (int u = 0; u < 16; ++u) acc[u] = 0.0;
        for (int tp = 0; tp < T; tp += 16) {
            #pragma unroll
            for (int u = 0; u < 16; ++u)
                acc[u] += s_sh[tp + u] * (double)Wc[(size_t)(tp + u) * T];
        }
        double r0 = (acc[0] + acc[1]) + (acc[2] + acc[3]);
        double r1 = (acc[4] + acc[5]) + (acc[6] + acc[7]);
        double r2 = (acc[8] + acc[9]) + (acc[10] + acc[11]);
        double r3 = (acc[12] + acc[13]) + (acc[14] + acc[15]);
        lg[tid] = ((r0 + r1) + (r2 + r3)) + (double)bias[tid];
    }
    __syncthreads();

    {
        const double v = lg[tid];
        int rank = 0;
        #pragma unroll 8
        for (int tp = 0; tp < T; ++tp) {
            double u = lg[tp];
            rank += (u > v) || (u == v && tp < tid);
        }
        if (rank < K) atomicOr(&flags[tid >> 5], 1u << (tid & 31));
    }
    __syncthreads();

    {
        if ((flags[tid >> 5] >> (tid & 31)) & 1u) {
            int pos = __popc(flags[tid >> 5] & ((1u << (tid & 31)) - 1u));
            for (int u2 = 0; u2 < (tid >> 5); ++u2) pos += __popc(flags[u2]);
            idx_out[(size_t)f * K + pos] = tid;
        }
    }
}

// ---------------------------------------------------------------------------
// K3: gather, high-occupancy. 256 threads = 4 waves, wave-per-output-row,
// grid = F*K/4 = 9216. 5 unrolled 64-lane f4 iters + 32-lane tail,
// nontemporal stores.
// ---------------------------------------------------------------------------
template <int T, int D, int K>
__global__ __launch_bounds__(256)
void gather_k(const float* __restrict__ x,
              const int* __restrict__ idx,
              float* __restrict__ out) {
    constexpr int N4 = D / 4;                // 352
    constexpr int RFULL = N4 / 64;           // 5
    constexpr int RREM  = N4 - RFULL * 64;   // 32

    const int lane = threadIdx.x & 63;
    const int row  = blockIdx.x * 4 + (threadIdx.x >> 6);   // global out-row
    const int f    = row / K;                                // magic-div (K const)
    const int t    = idx[row];

    const f4* src = (const f4*)(x + ((size_t)f * T + t) * D);
    f4*       dst = (f4*)(out + (size_t)row * D);
    f4 v0 = src[lane + 64 * 0];
    f4 v1 = src[lane + 64 * 1];
    f4 v2 = src[lane + 64 * 2];
    f4 v3 = src[lane + 64 * 3];
    f4 v4 = src[lane + 64 * 4];
    __builtin_nontemporal_store(v0, &dst[lane + 64 * 0]);
    __builtin_nontemporal_store(v1, &dst[lane + 64 * 1]);
    __builtin_nontemporal_store(v2, &dst[lane + 64 * 2]);
    __builtin_nontemporal_store(v3, &dst[lane + 64 * 3]);
    __builtin_nontemporal_store(v4, &dst[lane + 64 * 4]);
    if (lane < RREM) {
        f4 v5 = src[lane + 64 * RFULL];
        __builtin_nontemporal_store(v5, &dst[lane + 64 * RFULL]);
    }
}

// ---------------------------------------------------------------------------
// Generic fallback (runtime shape) — proven-correct fused kernel from R2-R8.
// ---------------------------------------------------------------------------
__global__ __launch_bounds__(1024)
void fused_select_kernel(const float* __restrict__ x,
                         const float* __restrict__ pre_w,
                         const float* __restrict__ pre_b,
                         const float* __restrict__ W,
                         const float* __restrict__ bias,
                         float* __restrict__ out,
                         int T, int D, int K) {
    __shared__ double   s_sh[1024];
    __shared__ double   lg[1024];
    __shared__ unsigned flags[32];
    __shared__ int      sel[576];

    const int f    = blockIdx.x;
    const int tid  = threadIdx.x;
    const int wave = tid >> 6;
    const int lane = tid & 63;
    const int nw   = blockDim.x >> 6;
    const int n4   = D >> 2;

    const f4* wv = (const f4*)pre_w;
    for (int t = wave; t < T; t += nw) {
        const f4* xr = (const f4*)(x + ((size_t)f * T + t) * D);
        double acc = 0.0;
        for (int p = lane; p < n4; p += 64) acc += dot4d(xr[p], wv[p]);
#pragma unroll
        for (int off = 32; off > 0; off >>= 1) acc += __shfl_down(acc, off);
        if (lane == 0) s_sh[t] = acc + (double)pre_b[0];
    }
    if (tid < 32) flags[tid] = 0u;
    __syncthreads();

    if (tid < T) {
        const float* Wc = W + tid;
        double a0 = 0, a1 = 0, a2 = 0, a3 = 0;
        int tp = 0;
        for (; tp + 4 <= T; tp += 4) {
            a0 += s_sh[tp + 0] * (double)Wc[(size_t)(tp + 0) * T];
            a1 += s_sh[tp + 1] * (double)Wc[(size_t)(tp + 1) * T];
            a2 += s_sh[tp + 2] * (double)Wc[(size_t)(tp + 2) * T];
            a3 += s_sh[tp + 3] * (double)Wc[(size_t)(tp + 3) * T];
        }
        for (; tp < T; ++tp) a0 += s_sh[tp] * (double)Wc[(size_t)tp * T];
        lg[tid] = ((a0 + a1) + (a2 + a3)) + (double)bias[tid];
    }
    __syncthreads();
    if (tid < T) {
        const double v = lg[tid];
        int rank = 0;
        for (int tp = 0; tp < T; ++tp) {
            double u = lg[tp];
            rank += (u > v) || (u == v && tp < tid);
        }
        if (rank < K) atomicOr(&flags[tid >> 5], 1u << (tid & 31));
    }
    __syncthreads();
    if (tid < T) {
        if ((flags[tid >> 5] >> (tid & 31)) & 1u) {
            int pos = __popc(flags[tid >> 5] & ((1u << (tid & 31)) - 1u));
            for (int u2 = 0; u2 < (tid >> 5); ++u2) pos += __popc(flags[u2]);
            sel[pos] = tid;
        }
    }
    __syncthreads();
    for (int k2 = wave; k2 < K; k2 += nw) {
        int t = sel[k2];
        const f4* src = (const f4*)(x + ((size_t)f * T + t) * D);
        f4*       dst = (f4*)(out + ((size_t)f * K + k2) * D);
        for (int p = lane; p < n4; p += 64)
            __builtin_nontemporal_store(src[p], &dst[p]);
    }
}

// ---------------------------------------------------------------------------
extern "C" void kernel_launch(void* const* d_in, const int* in_sizes, int n_in,
                              void* d_out, int out_size, void* d_ws, size_t ws_size,
                              hipStream_t stream) {
    const float* x     = (const float*)d_in[0];
    const float* pre_w = (const float*)d_in[1];
    const float* pre_b = (const float*)d_in[2];
    const float* W     = (const float*)d_in[3];
    const float* bias  = (const float*)d_in[4];
    float* outp = (float*)d_out;

    const int D = in_sizes[1];          // pre_w is [1, D]
    const int T = in_sizes[4];          // trans_bias is [T]
    const int F = in_sizes[0] / (T * D);
    const int K = out_size / (F * D);

    if (T == 576 && D == 1408 && K == 144 && (F * T) % 64 == 0 && (F * K) % 4 == 0) {
        double* s_buf = (double*)d_ws;
        int*    idx   = (int*)((char*)d_ws + (size_t)F * T * sizeof(double));

        score_k<576, 1408><<<(F * T) / 64, 256, 0, stream>>>(x, pre_w, pre_b, s_buf);
        select_k<576, 144><<<F, 576, 0, stream>>>(s_buf, W, bias, idx);
        gather_k<576, 1408, 144><<<(F * K) / 4, 256, 0, stream>>>(x, idx, outp);
    } else {
        fused_select_kernel<<<F, 1024, 0, stream>>>(x, pre_w, pre_b, W, bias,
                                                    outp, T, D, K);
    }
}